// Round 6
// baseline (69.972 us; speedup 1.0000x reference)
//
#include <hip/hip_runtime.h>

// B=32 rows, N=8192, K=256. Straight-through estimator forward value
// == hard one-hot-sum + sample_memory (soft terms cancel numerically).
//
// R6: full-chip selection. K1 (256 blocks) computes keys + per-segment
// 8-bit hists. K2 (256 blocks, 8 per row) redundantly selects the row's
// exact threshold T (8-bit pick from hists, then 12+12-bit refine over
// the ~900 candidates in LDS), computes index-order tie ranks, and each
// block emits only its own 1024-elem segment with pure float4 stores.
// No global atomics anywhere -> deterministic.

#define NROW 32
#define NCOL 8192
#define KSEL 256

__device__ __forceinline__ unsigned float_to_key(float f) {
    unsigned u = __float_as_uint(f);
    return (u & 0x80000000u) ? ~u : (u | 0x80000000u);  // monotone
}

// ---------------- K1: keys + per-segment 8-bit hist ----------------
__global__ __launch_bounds__(256) void k1(
    const float* __restrict__ logits, const float* __restrict__ noise,
    const float* __restrict__ mem,
    unsigned* __restrict__ keys, unsigned* __restrict__ ghist)
{
    __shared__ unsigned h[4][257];            // wave-private, +1 pad (bank shift)
    const int tid  = threadIdx.x;
    const int wave = tid >> 6;
    const int base = blockIdx.x * 1024 + tid * 4;

    float4 lg = *(const float4*)(logits + base);
    float4 no = *(const float4*)(noise  + base);
    float4 mm = *(const float4*)(mem    + base);

    h[0][tid] = 0u; h[1][tid] = 0u; h[2][tid] = 0u; h[3][tid] = 0u;
    if (tid < 4) h[tid][256] = 0u;

    unsigned k0 = float_to_key(lg.x + no.x + mm.x * -1000.0f);
    unsigned k1v = float_to_key(lg.y + no.y + mm.y * -1000.0f);
    unsigned k2v = float_to_key(lg.z + no.z + mm.z * -1000.0f);
    unsigned k3v = float_to_key(lg.w + no.w + mm.w * -1000.0f);

    *(uint4*)(keys + base) = make_uint4(k0, k1v, k2v, k3v);

    __syncthreads();
    unsigned* hw = h[wave];
    atomicAdd(&hw[k0  >> 24], 1u);
    atomicAdd(&hw[k1v >> 24], 1u);
    atomicAdd(&hw[k2v >> 24], 1u);
    atomicAdd(&hw[k3v >> 24], 1u);
    __syncthreads();

    ghist[blockIdx.x * 256 + tid] =
        h[0][tid] + h[1][tid] + h[2][tid] + h[3][tid];
}

// ---------------- K2: redundant per-row select, per-segment emit ----------------
__global__ __launch_bounds__(256) void k2(
    const unsigned* __restrict__ keys, const unsigned* __restrict__ ghist,
    const float* __restrict__ mem, float* __restrict__ out)
{
    __shared__ unsigned hist[4096];
    __shared__ unsigned wp[4];
    __shared__ unsigned wp8[8][4];
    __shared__ unsigned sh_d, sh_need;

    const int tid  = threadIdx.x;
    const int wave = tid >> 6;
    const int lane = tid & 63;
    const int r = blockIdx.x >> 3;           // row
    const int s = blockIdx.x & 7;            // my output segment
    const int rowbase = r * NCOL;

    // ---- load the row's full 8192 keys (8 x uint4 per thread) + my mem ----
    unsigned key[8][4];
#pragma unroll
    for (int j = 0; j < 8; ++j) {
        uint4 v = *(const uint4*)(keys + rowbase + j * 1024 + tid * 4);
        key[j][0] = v.x; key[j][1] = v.y; key[j][2] = v.z; key[j][3] = v.w;
    }
    float4 mm = *(const float4*)(mem + rowbase + s * 1024 + tid * 4);

    // zero refine hist while loads are in flight
#pragma unroll
    for (int i = tid; i < 4096; i += 256) hist[i] = 0u;

    // ---- L0 pick: 8-bit bins from ghist; thread t owns bin 255-t ----
    unsigned c = 0;
#pragma unroll
    for (int j = 0; j < 8; ++j) c += ghist[(r * 8 + j) * 256 + (255 - tid)];
    unsigned sc = c;
#pragma unroll
    for (int off = 1; off < 64; off <<= 1) {
        unsigned nv = __shfl_up(sc, off, 64);
        if (lane >= off) sc += nv;
    }
    if (lane == 63) wp[wave] = sc;
    __syncthreads();                                   // B1
    {
        unsigned add = 0;
        for (int w = 0; w < wave; ++w) add += wp[w];
        unsigned incl = sc + add, excl = incl - c;
        if (incl >= KSEL && excl < KSEL) { sh_d = 255u - (unsigned)tid; sh_need = KSEL - excl; }
    }
    __syncthreads();                                   // B2
    const unsigned b0 = sh_d;
    unsigned need = sh_need;

    // ---- refine 1: bits [23:12] among top-byte==b0 candidates ----
#pragma unroll
    for (int j = 0; j < 8; ++j)
#pragma unroll
        for (int i = 0; i < 4; ++i)
            if ((key[j][i] >> 24) == b0)
                atomicAdd(&hist[(key[j][i] >> 12) & 4095u], 1u);
    __syncthreads();                                   // B3
    {
        unsigned cc[16], tot = 0;
#pragma unroll
        for (int j2 = 0; j2 < 16; ++j2) { cc[j2] = hist[4095 - 16 * tid - j2]; tot += cc[j2]; }
        unsigned s2 = tot;
#pragma unroll
        for (int off = 1; off < 64; off <<= 1) {
            unsigned nv = __shfl_up(s2, off, 64);
            if (lane >= off) s2 += nv;
        }
        if (lane == 63) wp[wave] = s2;
        __syncthreads();                               // B4
        unsigned add = 0;
        for (int w = 0; w < wave; ++w) add += wp[w];
        unsigned cum = s2 + add - tot;                 // exclusive prefix
#pragma unroll
        for (int j2 = 0; j2 < 16; ++j2) {
            unsigned nc = cum + cc[j2];
            if (nc >= need && cum < need) { sh_d = 4095u - 16u * tid - j2; sh_need = need - cum; }
            cum = nc;
        }
    }
    __syncthreads();                                   // B5
    const unsigned p20 = (b0 << 12) | sh_d;
    need = sh_need;

    // ---- refine 2: bits [11:0] among (key>>12)==p20 ----
#pragma unroll
    for (int i = tid; i < 4096; i += 256) hist[i] = 0u;
    __syncthreads();                                   // B6
#pragma unroll
    for (int j = 0; j < 8; ++j)
#pragma unroll
        for (int i = 0; i < 4; ++i)
            if ((key[j][i] >> 12) == p20)
                atomicAdd(&hist[key[j][i] & 4095u], 1u);
    __syncthreads();                                   // B7
    {
        unsigned cc[16], tot = 0;
#pragma unroll
        for (int j2 = 0; j2 < 16; ++j2) { cc[j2] = hist[4095 - 16 * tid - j2]; tot += cc[j2]; }
        unsigned s2 = tot;
#pragma unroll
        for (int off = 1; off < 64; off <<= 1) {
            unsigned nv = __shfl_up(s2, off, 64);
            if (lane >= off) s2 += nv;
        }
        if (lane == 63) wp[wave] = s2;
        __syncthreads();                               // B8
        unsigned add = 0;
        for (int w = 0; w < wave; ++w) add += wp[w];
        unsigned cum = s2 + add - tot;
#pragma unroll
        for (int j2 = 0; j2 < 16; ++j2) {
            unsigned nc = cum + cc[j2];
            if (nc >= need && cum < need) { sh_d = 4095u - 16u * tid - j2; sh_need = need - cum; }
            cum = nc;
        }
    }
    __syncthreads();                                   // B9
    const unsigned T     = (p20 << 12) | sh_d;         // exact K-th largest key
    const unsigned needF = sh_need;                    // ties kept (lowest index)

    // ---- index-order tie ranks: 8 per-segment scans over thread order ----
    unsigned e[8], pfx[8];
#pragma unroll
    for (int j = 0; j < 8; ++j) {
        unsigned cnt = 0;
#pragma unroll
        for (int i = 0; i < 4; ++i) cnt += (key[j][i] == T) ? 1u : 0u;
        e[j] = cnt;
        unsigned ss = cnt;
#pragma unroll
        for (int off = 1; off < 64; off <<= 1) {
            unsigned nv = __shfl_up(ss, off, 64);
            if (lane >= off) ss += nv;
        }
        if (lane == 63) wp8[j][wave] = ss;
        pfx[j] = ss - cnt;                             // intra-wave exclusive
    }
    __syncthreads();                                   // B10
    unsigned rank = 0;
    for (int j = 0; j < s; ++j)
        rank += wp8[j][0] + wp8[j][1] + wp8[j][2] + wp8[j][3];  // full earlier segments
    rank += pfx[s];
    for (int w = 0; w < wave; ++w) rank += wp8[s][w];           // earlier threads, my segment

    // ---- emit my segment: out = indicator + mem (pure stores) ----
    float o[4];
#pragma unroll
    for (int i = 0; i < 4; ++i) {
        unsigned k = key[s][i];
        float sel;
        if (k > T)       sel = 1.0f;
        else if (k == T) { sel = (rank < needF) ? 1.0f : 0.0f; ++rank; }
        else             sel = 0.0f;
        o[i] = sel;
    }
    o[0] += mm.x; o[1] += mm.y; o[2] += mm.z; o[3] += mm.w;
    *(float4*)(out + rowbase + s * 1024 + tid * 4) = make_float4(o[0], o[1], o[2], o[3]);
}

extern "C" void kernel_launch(void* const* d_in, const int* in_sizes, int n_in,
                              void* d_out, int out_size, void* d_ws, size_t ws_size,
                              hipStream_t stream) {
    const float* logits = (const float*)d_in[0];
    const float* noise  = (const float*)d_in[1];
    const float* mem    = (const float*)d_in[2];
    float* out = (float*)d_out;

    unsigned* keys  = (unsigned*)d_ws;                              // 1 MB
    unsigned* ghist = (unsigned*)((char*)d_ws + NROW * NCOL * 4);   // 256 KB

    k1<<<256, 256, 0, stream>>>(logits, noise, mem, keys, ghist);
    k2<<<256, 256, 0, stream>>>(keys, ghist, mem, out);
}